// Round 1
// baseline (310.963 us; speedup 1.0000x reference)
//
#include <hip/hip_runtime.h>
#include <math.h>

#define D 512
#define H 8
#define DH 64
#define S 4096
#define FF 1024

typedef __attribute__((ext_vector_type(8))) short bf16x8;
typedef __attribute__((ext_vector_type(4))) float f32x4;

__device__ __forceinline__ unsigned short f2bf(float f) {
    union { float f; unsigned u; } c; c.f = f;
    unsigned r = (c.u + 0x7fff + ((c.u >> 16) & 1)) >> 16;
    return (unsigned short)r;
}

// ---------------- transpose-convert: w [K][N] fp32 -> wT [N][K] bf16 ----------------
__global__ __launch_bounds__(256) void transpose_w(const float* __restrict__ w,
                                                   unsigned short* __restrict__ wT,
                                                   int K, int N) {
    __shared__ unsigned short tile[32][33];
    int n0 = blockIdx.x * 32, k0 = blockIdx.y * 32;
    int tx = threadIdx.x & 31, ty = threadIdx.x >> 5;  // ty 0..7
#pragma unroll
    for (int i = 0; i < 32; i += 8)
        tile[ty + i][tx] = f2bf(w[(size_t)(k0 + ty + i) * N + n0 + tx]);
    __syncthreads();
#pragma unroll
    for (int i = 0; i < 32; i += 8)
        wT[(size_t)(n0 + ty + i) * K + k0 + tx] = tile[tx][ty + i];
}

// ---------------- transpose V slice of qkv (bf16): vT[d][s] = qkv[s][1024+d] --------
__global__ __launch_bounds__(256) void transpose_v(const unsigned short* __restrict__ qkv,
                                                   unsigned short* __restrict__ vT) {
    __shared__ unsigned short tile[32][33];
    int s0 = blockIdx.x * 32, d0 = blockIdx.y * 32;
    int tx = threadIdx.x & 31, ty = threadIdx.x >> 5;
#pragma unroll
    for (int i = 0; i < 32; i += 8)
        tile[ty + i][tx] = qkv[(size_t)(s0 + ty + i) * (3 * D) + 2 * D + d0 + tx];
    __syncthreads();
#pragma unroll
    for (int i = 0; i < 32; i += 8)
        vT[(size_t)(d0 + ty + i) * S + s0 + tx] = tile[tx][ty + i];
}

// ---------------- layernorm: fp32 [rows][512] -> bf16, one block per row -----------
__global__ __launch_bounds__(256) void ln_kernel(const float* __restrict__ x,
                                                 const float* __restrict__ g,
                                                 const float* __restrict__ bta,
                                                 unsigned short* __restrict__ out) {
    int row = blockIdx.x, tid = threadIdx.x;
    const float* xr = x + (size_t)row * D;
    float2 v = *(const float2*)(xr + tid * 2);
    float s = v.x + v.y;
    float sq = v.x * v.x + v.y * v.y;
#pragma unroll
    for (int m = 1; m < 64; m <<= 1) { s += __shfl_xor(s, m); sq += __shfl_xor(sq, m); }
    __shared__ float red[8];
    int wave = tid >> 6, lane = tid & 63;
    if (lane == 0) { red[wave] = s; red[4 + wave] = sq; }
    __syncthreads();
    s = red[0] + red[1] + red[2] + red[3];
    sq = red[4] + red[5] + red[6] + red[7];
    float mu = s * (1.f / D);
    float var = sq * (1.f / D) - mu * mu;
    float rstd = rsqrtf(var + 1e-5f);
    int i = tid * 2;
    float2 gg = *(const float2*)(g + i);
    float2 bb = *(const float2*)(bta + i);
    out[(size_t)row * D + i]     = f2bf((v.x - mu) * rstd * gg.x + bb.x);
    out[(size_t)row * D + i + 1] = f2bf((v.y - mu) * rstd * gg.y + bb.y);
}

// ---------------- GEMM: C[M][N] = A[M][K](bf16) * BT[N][K](bf16)^T + bias (+epi) ----
#define BM 128
#define BN 128
#define BK 32
#define LDT 40  // BK + 8 elements, keeps 16B alignment (80B rows)

enum { EPI_BF16 = 0, EPI_RESID_F32 = 1, EPI_GELU_BF16 = 2 };

template <int EPI>
__global__ __launch_bounds__(256, 2) void gemm_kernel(const unsigned short* __restrict__ A,
                                                      const unsigned short* __restrict__ BT,
                                                      const float* __restrict__ bias,
                                                      const float* __restrict__ resid,
                                                      void* __restrict__ out,
                                                      int M, int N, int K) {
    __shared__ __align__(16) unsigned short sA[BM * LDT];
    __shared__ __align__(16) unsigned short sB[BN * LDT];
    int tid = threadIdx.x;
    int wave = tid >> 6, lane = tid & 63;
    int quad = lane >> 4, l16 = lane & 15;
    int wr = (wave >> 1) * 64, wc = (wave & 1) * 64;
    int m0 = blockIdx.y * BM, n0 = blockIdx.x * BN;

    f32x4 acc[4][4];
#pragma unroll
    for (int i = 0; i < 4; i++)
#pragma unroll
        for (int j = 0; j < 4; j++) acc[i][j] = (f32x4){0.f, 0.f, 0.f, 0.f};

    int ar = tid >> 2;             // 0..63
    int ac = (tid & 3) * 8;        // 0,8,16,24
    const unsigned short* Ap = A + (size_t)(m0 + ar) * K + ac;
    const unsigned short* Ap2 = Ap + (size_t)64 * K;
    const unsigned short* Bp = BT + (size_t)(n0 + ar) * K + ac;
    const unsigned short* Bp2 = Bp + (size_t)64 * K;
    unsigned short* sAw = sA + ar * LDT + ac;
    unsigned short* sAw2 = sA + (ar + 64) * LDT + ac;
    unsigned short* sBw = sB + ar * LDT + ac;
    unsigned short* sBw2 = sB + (ar + 64) * LDT + ac;

    for (int k0 = 0; k0 < K; k0 += BK) {
        bf16x8 a0 = *(const bf16x8*)(Ap + k0);
        bf16x8 a1 = *(const bf16x8*)(Ap2 + k0);
        bf16x8 b0 = *(const bf16x8*)(Bp + k0);
        bf16x8 b1 = *(const bf16x8*)(Bp2 + k0);
        __syncthreads();
        *(bf16x8*)sAw = a0;
        *(bf16x8*)sAw2 = a1;
        *(bf16x8*)sBw = b0;
        *(bf16x8*)sBw2 = b1;
        __syncthreads();
        bf16x8 af[4], bfr[4];
#pragma unroll
        for (int i = 0; i < 4; i++)
            af[i] = *(const bf16x8*)(sA + (wr + i * 16 + l16) * LDT + quad * 8);
#pragma unroll
        for (int i = 0; i < 4; i++)
            bfr[i] = *(const bf16x8*)(sB + (wc + i * 16 + l16) * LDT + quad * 8);
#pragma unroll
        for (int mi = 0; mi < 4; mi++)
#pragma unroll
            for (int ni = 0; ni < 4; ni++)
                acc[mi][ni] = __builtin_amdgcn_mfma_f32_16x16x32_bf16(af[mi], bfr[ni], acc[mi][ni], 0, 0, 0);
    }

#pragma unroll
    for (int mi = 0; mi < 4; mi++)
#pragma unroll
        for (int ni = 0; ni < 4; ni++)
#pragma unroll
            for (int r = 0; r < 4; r++) {
                int row = m0 + wr + mi * 16 + quad * 4 + r;
                int col = n0 + wc + ni * 16 + l16;
                float v = acc[mi][ni][r] + bias[col];
                size_t idx = (size_t)row * N + col;
                if constexpr (EPI == EPI_RESID_F32) {
                    ((float*)out)[idx] = v + resid[idx];
                } else if constexpr (EPI == EPI_GELU_BF16) {
                    v = 0.5f * v * (1.f + erff(v * 0.70710678118f));
                    ((unsigned short*)out)[idx] = f2bf(v);
                } else {
                    ((unsigned short*)out)[idx] = f2bf(v);
                }
            }
}

// ---------------- flash attention, causal, one 64-query block x one head ------------
#define LDK 72  // 64 + 8, rows 144B (16B-aligned)

__global__ __launch_bounds__(256, 2) void flash_kernel(const unsigned short* __restrict__ qkv,
                                                       const unsigned short* __restrict__ vT,
                                                       unsigned short* __restrict__ O) {
    __shared__ __align__(16) unsigned short sK[64 * LDK];
    __shared__ __align__(16) unsigned short sV[64 * LDK];
    __shared__ __align__(16) unsigned short sP[4 * 16 * LDK];
    int tid = threadIdx.x;
    int wave = tid >> 6, lane = tid & 63;
    int quad = lane >> 4, l16 = lane & 15;
    int qb = blockIdx.x, h = blockIdx.y;
    int q0 = qb * 64;

    // Q fragments (A-layout): row = l16, k = ks*32 + quad*8
    int qrow = q0 + wave * 16 + l16;
    bf16x8 qf0 = *(const bf16x8*)(qkv + (size_t)qrow * (3 * D) + h * DH + quad * 8);
    bf16x8 qf1 = *(const bf16x8*)(qkv + (size_t)qrow * (3 * D) + h * DH + 32 + quad * 8);

    f32x4 o_acc[4];
#pragma unroll
    for (int i = 0; i < 4; i++) o_acc[i] = (f32x4){0.f, 0.f, 0.f, 0.f};
    float m_i[4], l_i[4];
#pragma unroll
    for (int r = 0; r < 4; r++) { m_i[r] = -1e30f; l_i[r] = 0.f; }

    int sr = tid >> 3;          // 0..31
    int sc = (tid & 7) * 8;     // 0..56
    const float scale = 0.125f; // 1/sqrt(64)
    unsigned short* sPw = sP + wave * 16 * LDK;

    for (int j0 = 0; j0 <= q0; j0 += 64) {
        __syncthreads();  // previous iter's LDS reads complete
        // stage K tile [key][d]
        *(bf16x8*)(sK + sr * LDK + sc) =
            *(const bf16x8*)(qkv + (size_t)(j0 + sr) * (3 * D) + D + h * DH + sc);
        *(bf16x8*)(sK + (sr + 32) * LDK + sc) =
            *(const bf16x8*)(qkv + (size_t)(j0 + sr + 32) * (3 * D) + D + h * DH + sc);
        // stage V^T tile [d][key]
        *(bf16x8*)(sV + sr * LDK + sc) =
            *(const bf16x8*)(vT + (size_t)(h * DH + sr) * S + j0 + sc);
        *(bf16x8*)(sV + (sr + 32) * LDK + sc) =
            *(const bf16x8*)(vT + (size_t)(h * DH + sr + 32) * S + j0 + sc);
        __syncthreads();

        // S = Q K^T  (16 q-rows x 64 keys per wave)
        f32x4 s_acc[4];
#pragma unroll
        for (int i = 0; i < 4; i++) s_acc[i] = (f32x4){0.f, 0.f, 0.f, 0.f};
#pragma unroll
        for (int ni = 0; ni < 4; ni++) {
            bf16x8 b0 = *(const bf16x8*)(sK + (ni * 16 + l16) * LDK + quad * 8);
            bf16x8 b1 = *(const bf16x8*)(sK + (ni * 16 + l16) * LDK + 32 + quad * 8);
            s_acc[ni] = __builtin_amdgcn_mfma_f32_16x16x32_bf16(qf0, b0, s_acc[ni], 0, 0, 0);
            s_acc[ni] = __builtin_amdgcn_mfma_f32_16x16x32_bf16(qf1, b1, s_acc[ni], 0, 0, 0);
        }

        // online softmax (row = quad*4+r within wave's 16 rows)
        bool diag = (j0 == q0);
        int qbase = q0 + wave * 16 + quad * 4;
        float p[4][4];
#pragma unroll
        for (int r = 0; r < 4; r++) {
            float mx = -1e30f;
#pragma unroll
            for (int ni = 0; ni < 4; ni++) {
                float v = s_acc[ni][r] * scale;
                if (diag && (j0 + ni * 16 + l16 > qbase + r)) v = -1e30f;
                p[ni][r] = v;
                mx = fmaxf(mx, v);
            }
            mx = fmaxf(mx, __shfl_xor(mx, 1));
            mx = fmaxf(mx, __shfl_xor(mx, 2));
            mx = fmaxf(mx, __shfl_xor(mx, 4));
            mx = fmaxf(mx, __shfl_xor(mx, 8));
            float mnew = fmaxf(m_i[r], mx);
            float alpha = __expf(m_i[r] - mnew);
            float sum = 0.f;
#pragma unroll
            for (int ni = 0; ni < 4; ni++) {
                float e = __expf(p[ni][r] - mnew);
                p[ni][r] = e;
                sum += e;
            }
            sum += __shfl_xor(sum, 1);
            sum += __shfl_xor(sum, 2);
            sum += __shfl_xor(sum, 4);
            sum += __shfl_xor(sum, 8);
            l_i[r] = l_i[r] * alpha + sum;
            m_i[r] = mnew;
#pragma unroll
            for (int di = 0; di < 4; di++) o_acc[di][r] *= alpha;
        }

        // P: C-layout -> LDS -> A-layout
#pragma unroll
        for (int ni = 0; ni < 4; ni++)
#pragma unroll
            for (int r = 0; r < 4; r++)
                sPw[(quad * 4 + r) * LDK + ni * 16 + l16] = f2bf(p[ni][r]);
        __syncthreads();  // conservative: guarantee cross-lane LDS visibility

        // O += P V
#pragma unroll
        for (int ks = 0; ks < 2; ks++) {
            bf16x8 pa = *(const bf16x8*)(sPw + l16 * LDK + ks * 32 + quad * 8);
#pragma unroll
            for (int di = 0; di < 4; di++) {
                bf16x8 vb = *(const bf16x8*)(sV + (di * 16 + l16) * LDK + ks * 32 + quad * 8);
                o_acc[di] = __builtin_amdgcn_mfma_f32_16x16x32_bf16(pa, vb, o_acc[di], 0, 0, 0);
            }
        }
    }

    // epilogue: O[q][h*64+d] bf16, normalized by l
#pragma unroll
    for (int di = 0; di < 4; di++)
#pragma unroll
        for (int r = 0; r < 4; r++) {
            int row = q0 + wave * 16 + quad * 4 + r;
            int col = h * DH + di * 16 + l16;
            O[(size_t)row * D + col] = f2bf(o_acc[di][r] / l_i[r]);
        }
}

// ---------------- launch ----------------
extern "C" void kernel_launch(void* const* d_in, const int* in_sizes, int n_in,
                              void* d_out, int out_size, void* d_ws, size_t ws_size,
                              hipStream_t stream) {
    const float* x     = (const float*)d_in[0];
    const float* w_qkv = (const float*)d_in[1];
    const float* b_qkv = (const float*)d_in[2];
    const float* w_out = (const float*)d_in[3];
    const float* b_out = (const float*)d_in[4];
    const float* w_ff1 = (const float*)d_in[5];
    const float* b_ff1 = (const float*)d_in[6];
    const float* w_ff2 = (const float*)d_in[7];
    const float* b_ff2 = (const float*)d_in[8];
    const float* g1    = (const float*)d_in[9];
    const float* bt1   = (const float*)d_in[10];
    const float* g2    = (const float*)d_in[11];
    const float* bt2   = (const float*)d_in[12];

    char* ws = (char*)d_ws;
    size_t off = 0;
    auto alloc = [&](size_t bytes) {
        void* p = ws + off;
        off += (bytes + 255) & ~(size_t)255;
        return p;
    };
    unsigned short* hbuf   = (unsigned short*)alloc((size_t)S * D * 2);        // LN1 out (reused as LN2 out)
    unsigned short* qkvbuf = (unsigned short*)alloc((size_t)S * 3 * D * 2);    // qkv (reused as ff1 act)
    unsigned short* vTbuf  = (unsigned short*)alloc((size_t)D * S * 2);
    unsigned short* Obuf   = (unsigned short*)alloc((size_t)S * D * 2);
    float*          x2buf  = (float*)alloc((size_t)S * D * 4);
    unsigned short* wqkvT  = (unsigned short*)alloc((size_t)3 * D * D * 2);
    unsigned short* woutT  = (unsigned short*)alloc((size_t)D * D * 2);
    unsigned short* wff1T  = (unsigned short*)alloc((size_t)FF * D * 2);
    unsigned short* wff2T  = (unsigned short*)alloc((size_t)D * FF * 2);
    unsigned short* h2buf  = hbuf;     // reuse
    unsigned short* ff1buf = qkvbuf;   // reuse

    // weight transposes (fp32 -> bf16, B^T layout)
    transpose_w<<<dim3(3 * D / 32, D / 32), 256, 0, stream>>>(w_qkv, wqkvT, D, 3 * D);
    transpose_w<<<dim3(D / 32, D / 32), 256, 0, stream>>>(w_out, woutT, D, D);
    transpose_w<<<dim3(FF / 32, D / 32), 256, 0, stream>>>(w_ff1, wff1T, D, FF);
    transpose_w<<<dim3(D / 32, FF / 32), 256, 0, stream>>>(w_ff2, wff2T, FF, D);

    // LN1
    ln_kernel<<<S, 256, 0, stream>>>(x, g1, bt1, hbuf);
    // QKV
    gemm_kernel<EPI_BF16><<<dim3(3 * D / BN, S / BM), 256, 0, stream>>>(
        hbuf, wqkvT, b_qkv, nullptr, qkvbuf, S, 3 * D, D);
    // V transpose for flash
    transpose_v<<<dim3(S / 32, D / 32), 256, 0, stream>>>(qkvbuf, vTbuf);
    // attention
    flash_kernel<<<dim3(S / 64, H), 256, 0, stream>>>(qkvbuf, vTbuf, Obuf);
    // out projection + residual -> x2 (fp32)
    gemm_kernel<EPI_RESID_F32><<<dim3(D / BN, S / BM), 256, 0, stream>>>(
        Obuf, woutT, b_out, x, x2buf, S, D, D);
    // LN2
    ln_kernel<<<S, 256, 0, stream>>>(x2buf, g2, bt2, h2buf);
    // FF1 + GELU
    gemm_kernel<EPI_GELU_BF16><<<dim3(FF / BN, S / BM), 256, 0, stream>>>(
        h2buf, wff1T, b_ff1, nullptr, ff1buf, S, FF, D);
    // FF2 + residual -> out (fp32)
    gemm_kernel<EPI_RESID_F32><<<dim3(D / BN, S / BM), 256, 0, stream>>>(
        ff1buf, wff2T, b_ff2, x2buf, (float*)d_out, S, D, FF);
}